// Round 2
// 640.774 us; speedup vs baseline: 1.0150x; 1.0150x over previous
//
#include <hip/hip_runtime.h>

// SplitConvStack: 3x depthwise dilated conv1d along W + ReLU, fused.
// x: [B=16, H=21, W=4096, C=64] fp32 NHWC; w1/w2/w3: [1,8,1,64].
// Stage dilations 1,2,4; SAME padding -> pad_lo = 3, 7, 14.
//
// One wave (64 lanes = 64 channels) streams a 256-wide W-chunk of one (b,h)
// row through a register software pipeline:
//   step t: load x[t+8] -> xf ; s1[t-4] from xf ; s2[t-11] from s1f ;
//           s3[t-25] from s2f -> store.
// FIFO sizes 16/16/32 divide the 32-step unrolled group and chunk bases are
// multiples of 32, so every FIFO index is a compile-time constant.
//
// Interior specialization (Round 0, resubmitted after infra failure):
// for chunks 1..14 every bounds predicate (z/v/u/wq in [0,W)) is statically
// true; the only step enables depend on (g,j), which are compile-time after
// peeling g=0,1,9. The steady loop g=2..8 is predicate-free: 1 unconditional
// load + 24 FMA + 3 max + 1 unconditional store per step. Chunks 0 and 15
// keep the generic runtime-checked path (wave-uniform branch). Blocks
// grouped so all 4 waves of a block share one chunk (uniform path/block).

#define W_DIM   4096
#define C_DIM   64
#define L_CHUNK 256
#define NCHUNK  16      // W / L_CHUNK
#define NROWS   336     // B*H = 16*21
#define WAVES_PER_BLOCK 4

// ---- FMA bodies (no bounds predicates; FIFO indices fold after unroll) ----
#define S1_BODY(j) do {                                                     \
    float a_ = 0.f;                                                         \
    _Pragma("unroll")                                                       \
    for (int k = 0; k < 8; ++k)                                             \
        a_ = fmaf(xf[((j) - 7 + k + 32) & 15], w1r[k], a_);                 \
    s1f[((j) - 4 + 32) & 15] = fmaxf(a_, 0.f);                              \
} while (0)

#define S2_BODY(j) do {                                                     \
    float a_ = 0.f;                                                         \
    _Pragma("unroll")                                                       \
    for (int k = 0; k < 8; ++k)                                             \
        a_ = fmaf(s1f[((j) - 18 + 2 * k + 32) & 15], w2r[k], a_);           \
    s2f[((j) - 11 + 32) & 31] = fmaxf(a_, 0.f);                             \
} while (0)

#define S3_STORE(j, dst) do {                                               \
    float a_ = 0.f;                                                         \
    _Pragma("unroll")                                                       \
    for (int k = 0; k < 8; ++k)                                             \
        a_ = fmaf(s2f[((j) - 39 + 4 * k + 64) & 31], w3r[k], a_);           \
    (dst) = fmaxf(a_, 0.f);                                                 \
} while (0)

__global__ __launch_bounds__(256, 4)
void splitconv_fused_kernel(const float* __restrict__ x,
                            const float* __restrict__ w1,
                            const float* __restrict__ w2,
                            const float* __restrict__ w3,
                            float* __restrict__ out) {
    const int lane  = threadIdx.x & 63;               // channel
    const int wid   = threadIdx.x >> 6;
    // block b: all 4 waves share chunk = b & 15 (uniform code path / block);
    // rows = (b>>4)*4 + wid, b>>4 in [0,84), 84*4 = 336 rows.
    const int chunk = blockIdx.x & (NCHUNK - 1);
    const int row   = (blockIdx.x >> 4) * WAVES_PER_BLOCK + wid;
    const int w0    = chunk * L_CHUNK;                // multiple of 256
    const int c     = lane;

    const float* __restrict__ xrow = x   + (size_t)row * (W_DIM * C_DIM) + c;
    float* __restrict__       orow = out + (size_t)row * (W_DIM * C_DIM) + c;

    // per-lane weights: w[k*C + c]
    float w1r[8], w2r[8], w3r[8];
#pragma unroll
    for (int k = 0; k < 8; ++k) {
        w1r[k] = w1[k * C_DIM + c];
        w2r[k] = w2[k * C_DIM + c];
        w3r[k] = w3[k * C_DIM + c];
    }

    float xf[16], s1f[16], s2f[32];
#pragma unroll
    for (int i = 0; i < 16; ++i) { xf[i] = 0.f; s1f[i] = 0.f; }
#pragma unroll
    for (int i = 0; i < 32; ++i) s2f[i] = 0.f;

    if (chunk >= 1 && chunk <= 14) {
        // ================= interior: zero runtime predicates =================
        // z(g,j) = w0 - 24 + 32g + j ; all z in [w0-24, w0+280] subset [0,W).
        const float* __restrict__ xp = xrow + (size_t)(w0 - 24) * C_DIM;
        float* __restrict__       op = orow + (size_t)w0 * C_DIM;

        // ---- g = 0: warm-up. s1 needed from v >= w0-21 (j>=15),
        //      s2 needed from u >= w0-14 (j>=29), no stores. ----
#pragma unroll
        for (int j = 0; j < 32; ++j) {
            xf[(j + 8) & 15] = xp[j * C_DIM];
            if (j >= 15) S1_BODY(j);
            if (j >= 29) S2_BODY(j);
        }
        xp += 32 * C_DIM;

        // ---- g = 1: full s1/s2; stores start at wq = w0 (j>=25). ----
#pragma unroll
        for (int j = 0; j < 32; ++j) {
            xf[(j + 8) & 15] = xp[j * C_DIM];
            S1_BODY(j);
            S2_BODY(j);
            if (j >= 25) S3_STORE(j, op[(j - 25) * C_DIM]);
        }
        xp += 32 * C_DIM;
        op += 7 * C_DIM;   // next store: g=2,j=0 -> rel 32*1 + 0 - 25 = 7

        // ---- g = 2..8: steady state, predicate-free. ----
#pragma unroll 1
        for (int g = 2; g <= 8; ++g) {
#pragma unroll
            for (int j = 0; j < 32; ++j) {
                xf[(j + 8) & 15] = xp[j * C_DIM];
                S1_BODY(j);
                S2_BODY(j);
                S3_STORE(j, op[j * C_DIM]);
            }
            xp += 32 * C_DIM;
            op += 32 * C_DIM;
        }

        // ---- g = 9: drain. loads needed through z = w0+280 (j<=16);
        //      s1/s2 through j<=24; stores through wq = w0+255 (j<25). ----
#pragma unroll
        for (int j = 0; j < 32; ++j) {
            if (j <= 16) xf[(j + 8) & 15] = xp[j * C_DIM];
            if (j <= 24) { S1_BODY(j); S2_BODY(j); }
            if (j <  25) S3_STORE(j, op[j * C_DIM]);
        }
    } else {
        // ================= edge chunks 0 and 15: generic path =================
        for (int g = 0; g < 10; ++g) {
            const int tbase = w0 - 32 + g * 32;       // == 0 (mod 32)
#pragma unroll
            for (int j = 0; j < 32; ++j) {
                const int t = tbase + j;              // t == j (mod 32)

                // ---- prefetch x[t+8] into xf[(t+8) % 16] ----
                {
                    const int z = t + 8;
                    float xv = 0.f;
                    if (z >= 0 && z < W_DIM && (z - w0) <= L_CHUNK + 24)
                        xv = xrow[(size_t)z * C_DIM];
                    xf[(j + 8) & 15] = xv;
                }

                // ---- stage 1 (d=1): s1[v], v = t-4 ----
                {
                    const int v = t - 4;
                    float a = 0.f;
#pragma unroll
                    for (int k = 0; k < 8; ++k)
                        a = fmaf(xf[(j - 7 + k + 32) & 15], w1r[k], a);
                    float s = fmaxf(a, 0.f);
                    s1f[(j - 4 + 32) & 15] = (v >= 0 && v < W_DIM) ? s : 0.f;
                }

                // ---- stage 2 (d=2): s2[u], u = t-11 ----
                {
                    const int u = t - 11;
                    float a = 0.f;
#pragma unroll
                    for (int k = 0; k < 8; ++k)
                        a = fmaf(s1f[(j - 18 + 2 * k + 32) & 15], w2r[k], a);
                    float s = fmaxf(a, 0.f);
                    s2f[(j - 11 + 32) & 31] = (u >= 0 && u < W_DIM) ? s : 0.f;
                }

                // ---- stage 3 (d=4): y[wq], wq = t-25 ----
                {
                    const int wq = t - 25;
                    if (wq >= w0 && wq < w0 + L_CHUNK) {
                        float a = 0.f;
#pragma unroll
                        for (int k = 0; k < 8; ++k)
                            a = fmaf(s2f[(j - 39 + 4 * k + 64) & 31], w3r[k], a);
                        orow[(size_t)wq * C_DIM] = fmaxf(a, 0.f);
                    }
                }
            }
        }
    }
}

extern "C" void kernel_launch(void* const* d_in, const int* in_sizes, int n_in,
                              void* d_out, int out_size, void* d_ws, size_t ws_size,
                              hipStream_t stream) {
    const float* x  = (const float*)d_in[0];
    const float* w1 = (const float*)d_in[1];
    const float* w2 = (const float*)d_in[2];
    const float* w3 = (const float*)d_in[3];
    float* out = (float*)d_out;

    const int totalWaves = NROWS * NCHUNK;                 // 5376
    const int blocks = totalWaves / WAVES_PER_BLOCK;       // 1344
    splitconv_fused_kernel<<<blocks, 256, 0, stream>>>(x, w1, w2, w3, out);
}

// Round 3
// 635.148 us; speedup vs baseline: 1.0240x; 1.0089x over previous
//
#include <hip/hip_runtime.h>

// SplitConvStack: 3x depthwise dilated conv1d along W + ReLU, fused.
// x: [B=16, H=21, W=4096, C=64] fp32 NHWC; w1/w2/w3: [1,8,1,64].
// Stage dilations 1,2,4; SAME padding -> pad_lo = 3, 7, 14.
//
// One wave (64 lanes = 64 channels) streams a 256-wide W-chunk of one (b,h)
// row through a register software pipeline:
//   step t: s1[t-4] from x ; s2[t-11] from s1f ; s3[t-25] from s2f -> store.
// s1f/s2f FIFO sizes 16/32 divide the 32-step unrolled group and chunk bases
// are multiples of 32, so every FIFO index is a compile-time constant.
//
// ROUND 2 -> 3: latency fix. rocprof showed VALUBusy 28% + HBM 29% + occ 28%
// (latency-bound); VGPR=60 proved the compiler was sinking loads next to
// uses (prefetch distance ~few steps, HBM miss ~900 cyc uncovered). Now x is
// double-buffered at GROUP granularity: group g's block issues all 32 loads
// for group g+1 into the idle buffer and computes from the other. The loop
// back-edge is a basic-block boundary, so loads are structurally forced to
// issue a full group (~32 steps of FMA work) before first use.
// launch_bounds relaxed to (256,3) so the +32-reg buffer cannot spill.
// Output stores are nontemporal (written once, never re-read) to keep the
// 344 MB write stream from evicting x in L2/L3.

#define W_DIM   4096
#define C_DIM   64
#define L_CHUNK 256
#define NCHUNK  16      // W / L_CHUNK
#define NROWS   336     // B*H = 16*21
#define WAVES_PER_BLOCK 4

// ---- FMA bodies (indices fold to constants after unroll) ----
// stage 1 over double-buffered x: taps x[t-7..t]; i = j-7+k. For i<0 the
// value lives in the PREVIOUS group's buffer at slot i+32. Both j and k are
// compile-time constants, so the ternary folds; &31 keeps the dead arm's
// subscript in range.
#define S1X(j, CUR, PRV) do {                                               \
    float a_ = 0.f;                                                         \
    _Pragma("unroll")                                                       \
    for (int k = 0; k < 8; ++k) {                                           \
        const int i_ = (j) - 7 + k;                                         \
        const float xv_ = (i_ >= 0) ? CUR[i_ & 31] : PRV[(i_ + 32) & 31];   \
        a_ = fmaf(xv_, w1r[k], a_);                                         \
    }                                                                       \
    s1f[((j) - 4 + 32) & 15] = fmaxf(a_, 0.f);                              \
} while (0)

#define S2_BODY(j) do {                                                     \
    float a_ = 0.f;                                                         \
    _Pragma("unroll")                                                       \
    for (int k = 0; k < 8; ++k)                                             \
        a_ = fmaf(s1f[((j) - 18 + 2 * k + 32) & 15], w2r[k], a_);           \
    s2f[((j) - 11 + 32) & 31] = fmaxf(a_, 0.f);                             \
} while (0)

#define S3_NT(j, pdst) do {                                                 \
    float a_ = 0.f;                                                         \
    _Pragma("unroll")                                                       \
    for (int k = 0; k < 8; ++k)                                             \
        a_ = fmaf(s2f[((j) - 39 + 4 * k + 64) & 31], w3r[k], a_);           \
    __builtin_nontemporal_store(fmaxf(a_, 0.f), (pdst));                    \
} while (0)

__global__ __launch_bounds__(256, 3)
void splitconv_fused_kernel(const float* __restrict__ x,
                            const float* __restrict__ w1,
                            const float* __restrict__ w2,
                            const float* __restrict__ w3,
                            float* __restrict__ out) {
    const int lane  = threadIdx.x & 63;               // channel
    const int wid   = threadIdx.x >> 6;
    // block b: all 4 waves share chunk = b & 15 (uniform code path / block);
    // rows = (b>>4)*4 + wid, b>>4 in [0,84), 84*4 = 336 rows.
    const int chunk = blockIdx.x & (NCHUNK - 1);
    const int row   = (blockIdx.x >> 4) * WAVES_PER_BLOCK + wid;
    const int w0    = chunk * L_CHUNK;                // multiple of 256
    const int c     = lane;

    const float* __restrict__ xrow = x   + (size_t)row * (W_DIM * C_DIM) + c;
    float* __restrict__       orow = out + (size_t)row * (W_DIM * C_DIM) + c;

    // per-lane weights: w[k*C + c]
    float w1r[8], w2r[8], w3r[8];
#pragma unroll
    for (int k = 0; k < 8; ++k) {
        w1r[k] = w1[k * C_DIM + c];
        w2r[k] = w2[k * C_DIM + c];
        w3r[k] = w3[k * C_DIM + c];
    }

    float s1f[16], s2f[32];
#pragma unroll
    for (int i = 0; i < 16; ++i) s1f[i] = 0.f;
#pragma unroll
    for (int i = 0; i < 32; ++i) s2f[i] = 0.f;

    if (chunk >= 1 && chunk <= 14) {
        // ============ interior: no runtime predicates, deep prefetch ========
        // Group g computes steps t = w0-32+32g+j (j=0..31); its x data
        // x[w0-32+32g .. w0-1+32g] was loaded during group g-1 into the
        // buffer it now reads (xa for even g, xb for odd g). Group g issues
        // the loads x[w0+32g+j] for group g+1 into the other buffer.
        float xa[32], xb[32];
        const float* __restrict__ xp = xrow + (size_t)(w0 - 32) * C_DIM;
        float* __restrict__       op = orow + (size_t)w0 * C_DIM;

        // prologue: group-0 data -> xa   (x[w0-32 .. w0-1])
#pragma unroll
        for (int j = 0; j < 32; ++j) xa[j] = xp[j * C_DIM];
        xp += 32 * C_DIM;                              // -> x[w0]

        // ---- g=0 (warm-up): compute from xa; s1 j>=15, s2 j>=29; load xb ----
#pragma unroll
        for (int j = 0; j < 32; ++j) {
            xb[j] = xp[j * C_DIM];                     // x[w0+j] (g=1 data)
            if (j >= 15) S1X(j, xa, xa);               // all taps in xa
            if (j >= 29) S2_BODY(j);
        }
        xp += 32 * C_DIM;

        // ---- g=1: full s1/s2 from xb (tail from xa); stores j>=25; load xa ----
#pragma unroll
        for (int j = 0; j < 32; ++j) {
            xa[j] = xp[j * C_DIM];                     // x[w0+32+j] (g=2 data)
            S1X(j, xb, xa);                            // PRV reads xa[25..31] at j<7,
            S2_BODY(j);                                // overwritten only at j>=25
            if (j >= 25) S3_NT(j, &op[(j - 25) * C_DIM]);
        }
        xp += 32 * C_DIM;
        op += 7 * C_DIM;   // next store: g=2,j=0 -> w0+7

        // ---- g=2..7: steady pairs (even: compute xa / load xb; odd: swap) ----
#pragma unroll 1
        for (int p = 0; p < 3; ++p) {
#pragma unroll
            for (int j = 0; j < 32; ++j) {             // even group
                xb[j] = xp[j * C_DIM];
                S1X(j, xa, xb);                        // PRV=xb (g-1 tail)
                S2_BODY(j);
                S3_NT(j, &op[j * C_DIM]);
            }
            xp += 32 * C_DIM; op += 32 * C_DIM;
#pragma unroll
            for (int j = 0; j < 32; ++j) {             // odd group
                xa[j] = xp[j * C_DIM];
                S1X(j, xb, xa);
                S2_BODY(j);
                S3_NT(j, &op[j * C_DIM]);
            }
            xp += 32 * C_DIM; op += 32 * C_DIM;
        }

        // ---- g=8: full compute from xa; load only j<=24 (z = w0+256+j) ----
#pragma unroll
        for (int j = 0; j < 32; ++j) {
            if (j <= 24) xb[j] = xp[j * C_DIM];        // writes xb[0..24];
            S1X(j, xa, xb);                            // PRV reads xb[25..31] (g7 tail)
            S2_BODY(j);
            S3_NT(j, &op[j * C_DIM]);
        }
        op += 32 * C_DIM;

        // ---- g=9 (drain): s1/s2 j<=24; stores j<25; no loads ----
#pragma unroll
        for (int j = 0; j < 32; ++j) {
            if (j <= 24) { S1X(j, xb, xa); S2_BODY(j); }
            if (j <  25) S3_NT(j, &op[j * C_DIM]);
        }
    } else {
        // ================= edge chunks 0 and 15: generic path =================
        float xf[16];
#pragma unroll
        for (int i = 0; i < 16; ++i) xf[i] = 0.f;

        for (int g = 0; g < 10; ++g) {
            const int tbase = w0 - 32 + g * 32;       // == 0 (mod 32)
#pragma unroll
            for (int j = 0; j < 32; ++j) {
                const int t = tbase + j;              // t == j (mod 32)

                // ---- prefetch x[t+8] into xf[(t+8) % 16] ----
                {
                    const int z = t + 8;
                    float xv = 0.f;
                    if (z >= 0 && z < W_DIM && (z - w0) <= L_CHUNK + 24)
                        xv = xrow[(size_t)z * C_DIM];
                    xf[(j + 8) & 15] = xv;
                }

                // ---- stage 1 (d=1): s1[v], v = t-4 ----
                {
                    const int v = t - 4;
                    float a = 0.f;
#pragma unroll
                    for (int k = 0; k < 8; ++k)
                        a = fmaf(xf[(j - 7 + k + 32) & 15], w1r[k], a);
                    float s = fmaxf(a, 0.f);
                    s1f[(j - 4 + 32) & 15] = (v >= 0 && v < W_DIM) ? s : 0.f;
                }

                // ---- stage 2 (d=2): s2[u], u = t-11 ----
                {
                    const int u = t - 11;
                    float a = 0.f;
#pragma unroll
                    for (int k = 0; k < 8; ++k)
                        a = fmaf(s1f[(j - 18 + 2 * k + 32) & 15], w2r[k], a);
                    float s = fmaxf(a, 0.f);
                    s2f[(j - 11 + 32) & 31] = (u >= 0 && u < W_DIM) ? s : 0.f;
                }

                // ---- stage 3 (d=4): y[wq], wq = t-25 ----
                {
                    const int wq = t - 25;
                    if (wq >= w0 && wq < w0 + L_CHUNK) {
                        float a = 0.f;
#pragma unroll
                        for (int k = 0; k < 8; ++k)
                            a = fmaf(s2f[(j - 39 + 4 * k + 64) & 31], w3r[k], a);
                        __builtin_nontemporal_store(fmaxf(a, 0.f),
                                                    &orow[(size_t)wq * C_DIM]);
                    }
                }
            }
        }
    }
}

extern "C" void kernel_launch(void* const* d_in, const int* in_sizes, int n_in,
                              void* d_out, int out_size, void* d_ws, size_t ws_size,
                              hipStream_t stream) {
    const float* x  = (const float*)d_in[0];
    const float* w1 = (const float*)d_in[1];
    const float* w2 = (const float*)d_in[2];
    const float* w3 = (const float*)d_in[3];
    float* out = (float*)d_out;

    const int totalWaves = NROWS * NCHUNK;                 // 5376
    const int blocks = totalWaves / WAVES_PER_BLOCK;       // 1344
    splitconv_fused_kernel<<<blocks, 256, 0, stream>>>(x, w1, w2, w3, out);
}